// Round 13
// baseline (863.981 us; speedup 1.0000x reference)
//
#include <hip/hip_runtime.h>
#include <hip/hip_bf16.h>

typedef float f32x4 __attribute__((ext_vector_type(4)));
typedef float f32x2 __attribute__((ext_vector_type(2)));
typedef int   i32x4 __attribute__((ext_vector_type(4)));
typedef int   i32x8 __attribute__((ext_vector_type(8)));

#define LOG_SQRT_2PI 0.91893853320467274f

static constexpr int BSZ  = 16384;
static constexpr int OBSN = 376;
static constexpr int HD   = 512;
static constexpr int NACT = 17;

__device__ __forceinline__ unsigned char f2fp8(float v) {
  return (unsigned char)(__builtin_amdgcn_cvt_pk_fp8_f32(v, v, 0, false) & 0xFF);
}

__device__ __forceinline__ void gl16(const unsigned char* g, unsigned char* l) {
  __builtin_amdgcn_global_load_lds((const __attribute__((address_space(1))) void*)g,
                                   (__attribute__((address_space(3))) void*)l, 16, 0, 0);
}

// XCD-aware tile remap. Requires grid % 8 == 0.
__device__ __forceinline__ void xcd_map(int id, int gx, int gy, int& bx, int& by, int& bz) {
  int p = id & 7, l = id >> 3;
  bx = l % gx;
  int g = (l / gx) * 8 + p;
  by = g % gy;
  bz = g / gy;
}

// ---------------- prep kernels ----------------

// x [B,376] f32 -> [B,512] fp8 (zero pad)
__global__ void k_cvt_pad8(const float* __restrict__ src, unsigned char* __restrict__ dst) {
  long i = (long)blockIdx.x * 256 + threadIdx.x;
  if (i >= (long)BSZ * HD) return;
  long r = i >> 9;
  int  c = (int)(i & 511);
  dst[i] = f2fp8(c < OBSN ? src[r * OBSN + c] : 0.f);
}

// dst[n][k] = fp8(scale * src[k][n]); zero for k >= K. batched via blockIdx.z.
__global__ void k_packT8(const float* __restrict__ src, unsigned char* __restrict__ dst,
                         int K, int N, int Kpad, long sstride, long dstride, float scale) {
  __shared__ float t[32][33];
  src += (long)blockIdx.z * sstride;
  dst += (long)blockIdx.z * dstride;
  int k0 = blockIdx.y * 32, n0 = blockIdx.x * 32;
#pragma unroll
  for (int ii = 0; ii < 4; ++ii) {
    int i = ii * 8 + threadIdx.y;
    int k = k0 + i, n = n0 + threadIdx.x;
    t[i][threadIdx.x] = (k < K && n < N) ? src[(long)k * N + n] : 0.f;
  }
  __syncthreads();
#pragma unroll
  for (int ii = 0; ii < 4; ++ii) {
    int i = ii * 8 + threadIdx.y;
    int n = n0 + i, k = k0 + threadIdx.x;
    if (n < N && k < Kpad) dst[(long)n * Kpad + k] = f2fp8(scale * t[threadIdx.x][i]);
  }
}

// base-net weights -> FRAGMENT-PACKED fp8 x16, via LDS transpose (coalesced reads,
// contiguous 32 B fragment writes). Bit-exact verified.
__global__ void k_packwF(const float* __restrict__ aW, const float* __restrict__ cW,
                         unsigned char* __restrict__ dst) {
  __shared__ unsigned char sT[128 * 144];
  const int tid = threadIdx.x;            // 256
  const int z = blockIdx.z;               // 0..47
  const int t = blockIdx.y;               // 0..3
  const int ng = blockIdx.x;              // 0..3
  const int layer = z >> 4, zz = z & 15, net = zz >> 3, m = zz & 7;
  const float* src = (net ? aW : cW) + (long)(layer * 8 + m) * 262144;
#pragma unroll
  for (int i = 0; i < 64; ++i) {
    int lin = i * 256 + tid;
    int kl = lin >> 7, nl = lin & 127;
    float v = src[(long)(t * 128 + kl) * 512 + ng * 128 + nl];
    sT[nl * 144 + kl] = f2fp8(16.f * v);
  }
  __syncthreads();
#pragma unroll
  for (int f = 0; f < 2; ++f) {
    int fid = f * 256 + tid;
    int lane = fid & 63, nb_l = fid >> 6;
    int n_l = nb_l * 16 + (lane & 15);
    int klo = ((lane >> 4) & 3) * 32;
    uint4 lo = *(const uint4*)&sT[n_l * 144 + klo];
    uint4 hi = *(const uint4*)&sT[n_l * 144 + klo + 16];
    int nb = ng * 8 + nb_l;
    unsigned char* d = dst + ((((long)z * 4 + t) * 32 + nb) * 64 + lane) * 32;
    *(uint4*)d = lo;
    *(uint4*)(d + 16) = hi;
  }
}

// merged small packs: lb (merged biases), head weights (permuted-k), routing bias
__global__ void k_packmisc(const float* __restrict__ a_b, const float* __restrict__ c_b,
                           const float* __restrict__ aWf, const float* __restrict__ cWf,
                           const float* __restrict__ a_rb, const float* __restrict__ c_rb,
                           float* __restrict__ lb, unsigned char* __restrict__ dsta,
                           unsigned char* __restrict__ dstc, float* __restrict__ rb) {
  int i = blockIdx.x * 256 + threadIdx.x;
  if (i < 24576) {
    int layer = i >> 13, zz = (i >> 9) & 15, n = i & 511;
    int net = zz >> 3, m = zz & 7;
    lb[i] = (net ? a_b : c_b)[(layer * 8 + m) * 512 + n];
  } else if (i < 24576 + 131072) {
    int j = i - 24576;
    int n = j >> 12, kn = j & 4095;
    int hb = kn >> 9, rem = kn & 511, m = rem >> 6, u = kn & 63;
    int ko = m * 512 + hb * 64 + u;
    dsta[j] = (n < NACT) ? f2fp8(64.f * aWf[(long)ko * NACT + n]) : (unsigned char)0;
    dstc[j] = (n < 1)    ? f2fp8(64.f * cWf[ko])                  : (unsigned char)0;
  } else if (i < 24576 + 131072 + 384) {
    int j = i - 24576 - 131072;
    rb[j] = (j < 192) ? a_rb[j] : c_rb[j - 192];
  }
}

// out init: bias sums for actor/critic heads + logstd constants (cols 17/18).
__global__ void k_initout2(const float* __restrict__ a_bf, const float* __restrict__ c_bf,
                           const float* __restrict__ ls, float* __restrict__ out) {
  long i = (long)blockIdx.x * 256 + threadIdx.x;   // BSZ*20
  if (i >= (long)BSZ * 20) return;
  int o = (int)(i % 20);
  float v = 0.f;
  if (o < NACT) {
    for (int m = 0; m < 8; ++m) v += a_bf[m * NACT + o];
  } else if (o == 19) {
    for (int m = 0; m < 8; ++m) v += c_bf[m];
  } else if (o == 17) {
    for (int a = 0; a < NACT; ++a) v += -ls[a] - LOG_SQRT_2PI;
  } else {
    for (int a = 0; a < NACT; ++a) v += 0.5f + LOG_SQRT_2PI + ls[a];
  }
  out[i] = v;
}

// ---------------- unified MX fp8 GEMM (LDS path): encoder / routing ----------------
// OP: 1 = tanh -> fp8 (encoder-1); 5 = tanh->fp8 AND fp8(relu(tanh*temb)) (encoder-2)
//     4 = softmax over col-octets -> f32 (routing)
template <int OP>
__global__ __launch_bounds__(256, 4)
void k_gemm8(const unsigned char* __restrict__ A, const unsigned char* __restrict__ Bt,
             void* __restrict__ Cv, const float* __restrict__ bias,
             int N, int K, int lda, int ldc, int gx, int gy,
             const int* __restrict__ tidx, const float* __restrict__ temb,
             unsigned char* __restrict__ out2) {
  __shared__ alignas(16) unsigned char sA[128 * 128];
  __shared__ alignas(16) unsigned char sB[128 * 128];
  int bx, by, z;
  xcd_map(blockIdx.x, gx, gy, bx, by, z);
  const int tid  = threadIdx.x;
  const int wave = tid >> 6, lane = tid & 63;
  const int wr = (wave >> 1) * 64, wc = (wave & 1) * 64;
  const int row0 = by * 128, col0 = bx * 128;
  const int lcol = lane & 15, quad = lane >> 4;
  const int sw7 = lcol & 7;
  const int c0 = ((2 * quad)     ^ sw7) * 16;
  const int c1 = ((2 * quad + 1) ^ sw7) * 16;
  const int raA0 = (wr + lcol) * 128 + c0, raA1 = (wr + lcol) * 128 + c1;
  const int rbB0 = (wc + lcol) * 128 + c0, rbB1 = (wc + lcol) * 128 + c1;
  int aOff[4], bOff[4];
#pragma unroll
  for (int i = 0; i < 4; ++i) {
    int u = i * 256 + tid;
    int r = u >> 3, gc = (u & 7) ^ (r & 7);
    aOff[i] = (row0 + r) * lda + gc * 16;
    bOff[i] = (col0 + r) * K + gc * 16;
  }

  f32x4 acc[4][4] = {};

  for (int kt = 0; kt < K; kt += 128) {
#pragma unroll
    for (int i = 0; i < 4; ++i) gl16(A + aOff[i] + kt, &sA[i * 4096 + tid * 16]);
#pragma unroll
    for (int i = 0; i < 4; ++i) gl16(Bt + bOff[i] + kt, &sB[i * 4096 + tid * 16]);
    __syncthreads();
    i32x8 bv[4];
#pragma unroll
    for (int ni = 0; ni < 4; ++ni) {
      i32x4 blo = *(const i32x4*)&sB[rbB0 + ni * 2048];
      i32x4 bhi = *(const i32x4*)&sB[rbB1 + ni * 2048];
      bv[ni] = (i32x8){blo[0], blo[1], blo[2], blo[3], bhi[0], bhi[1], bhi[2], bhi[3]};
    }
#pragma unroll
    for (int mi = 0; mi < 4; ++mi) {
      i32x4 alo = *(const i32x4*)&sA[raA0 + mi * 2048];
      i32x4 ahi = *(const i32x4*)&sA[raA1 + mi * 2048];
      i32x8 af = (i32x8){alo[0], alo[1], alo[2], alo[3], ahi[0], ahi[1], ahi[2], ahi[3]};
#pragma unroll
      for (int ni = 0; ni < 4; ++ni)
        acc[mi][ni] = __builtin_amdgcn_mfma_scale_f32_16x16x128_f8f6f4(
            bv[ni], af, acc[mi][ni], 0, 0, 0, 0x7F, 0, 0x7F);
    }
    __syncthreads();
  }

#pragma unroll
  for (int ni = 0; ni < 4; ++ni) {
    int colb = col0 + wc + ni * 16 + quad * 4;
    if (colb >= N) continue;
    float4 bw = *(const float4*)&bias[colb];
#pragma unroll
    for (int mi = 0; mi < 4; ++mi) {
      int rowg = row0 + wr + mi * 16 + lcol;
      float v0 = acc[mi][ni][0] * 0.0625f + bw.x;
      float v1 = acc[mi][ni][1] * 0.0625f + bw.y;
      float v2 = acc[mi][ni][2] * 0.0625f + bw.z;
      float v3 = acc[mi][ni][3] * 0.0625f + bw.w;
      long idx = (long)rowg * ldc + colb;
      if (OP == 1) {
        float t0 = tanhf(v0), t1 = tanhf(v1), t2 = tanhf(v2), t3 = tanhf(v3);
        unsigned d = __builtin_amdgcn_cvt_pk_fp8_f32(t0, t1, 0, false);
        d = __builtin_amdgcn_cvt_pk_fp8_f32(t2, t3, d, true);
        *(unsigned*)&((unsigned char*)Cv)[idx] = d;
      } else if (OP == 5) {
        float t0 = tanhf(v0), t1 = tanhf(v1), t2 = tanhf(v2), t3 = tanhf(v3);
        unsigned d = __builtin_amdgcn_cvt_pk_fp8_f32(t0, t1, 0, false);
        d = __builtin_amdgcn_cvt_pk_fp8_f32(t2, t3, d, true);
        *(unsigned*)&((unsigned char*)Cv)[idx] = d;
        int tk = tidx[rowg];
        float4 te = *(const float4*)&temb[(long)tk * HD + colb];
        unsigned e = __builtin_amdgcn_cvt_pk_fp8_f32(fmaxf(t0 * te.x, 0.f), fmaxf(t1 * te.y, 0.f), 0, false);
        e = __builtin_amdgcn_cvt_pk_fp8_f32(fmaxf(t2 * te.z, 0.f), fmaxf(t3 * te.w, 0.f), e, true);
        *(unsigned*)&out2[idx] = e;
      } else if (OP == 4) {
        float mx = fmaxf(fmaxf(v0, v1), fmaxf(v2, v3));
        mx = fmaxf(mx, __shfl_xor(mx, 16));
        float e0 = __expf(v0 - mx), e1 = __expf(v1 - mx), e2 = __expf(v2 - mx), e3 = __expf(v3 - mx);
        float s = e0 + e1 + e2 + e3;
        s += __shfl_xor(s, 16);
        float inv = 1.f / s;
        *(float4*)&((float*)Cv)[idx] = make_float4(e0 * inv, e1 * inv, e2 * inv, e3 * inv);
      }
    }
  }
}

// ---------------- FUSED base-net layer: GEMM (8 modules) + routed combine (+head) ----
// g is now FRAGMENT-PACKED: gF[slab(64r)][net][module][t=k>>7][mi=r'>>4][lane][32 B]
// (lane = ((k>>5)&3)*16 + (r'&15)). Combine writes it with full-128B-line coverage;
// AMODE1 reads A-fragments DIRECTLY from global (lane*32 contiguous, like weights):
// no LDS staging, no vmcnt drains — fully unrolled K-loop, compiler-pipelined loads.
// AMODE0 (layer 1, A=fs8 row-major) keeps the proven LDS staging path.
template <int AMODE, int HEAD>
__global__ __launch_bounds__(512, 4)
void k_gemmF(const unsigned char* __restrict__ A, const unsigned char* __restrict__ Wp,
             const float* __restrict__ lb, const float* __restrict__ probs,
             unsigned char* __restrict__ g, int gy, int poffC, int poffA,
             const unsigned char* __restrict__ Wfc, const unsigned char* __restrict__ Wfa,
             float* __restrict__ outp) {
  __shared__ alignas(16) unsigned char sL[HEAD ? 65536 : 32768];
  int hb, slab, net;
  xcd_map(blockIdx.x, 8, gy, hb, slab, net);
  const int tid = threadIdx.x;
  const int w = tid >> 6, lane = tid & 63;
  const int lcol = lane & 15, quad = lane >> 4;
  const int ln3 = lane >> 3, sl = lane & 7;
  const int row0 = slab * 64;
  const int h0 = hb * 64;
  const int sw7 = lcol & 7;
  const int c0 = ((2 * quad)     ^ sw7) * 16;
  const int c1 = ((2 * quad + 1) ^ sw7) * 16;
  const int ch = sl ^ ln3;
  const unsigned char* wbase =
      Wp + (((long)(net * 8 + w) * 4 * 32 + hb * 4) * 64 + lane) * 32;

  f32x4 acc[4][4] = {};

  if (AMODE == 0) {
#pragma unroll
    for (int i = 0; i < 4; ++i) {
      int vb = w * 4 + i;
      int rr = (vb & 7) * 8 + ln3;
      gl16(A + (row0 + rr) * 512 + (vb >> 3) * 128 + ch * 16, &sL[(vb * 64 + lane) * 16]);
    }
    __syncthreads();
#pragma unroll
    for (int t = 0; t < 4; ++t) {
      i32x8 bv[4];
#pragma unroll
      for (int ni = 0; ni < 4; ++ni) {
        i32x4 lo = *(const i32x4*)(wbase + t * 65536 + ni * 2048);
        i32x4 hi = *(const i32x4*)(wbase + t * 65536 + ni * 2048 + 16);
        bv[ni] = (i32x8){lo[0], lo[1], lo[2], lo[3], hi[0], hi[1], hi[2], hi[3]};
      }
      __builtin_amdgcn_s_setprio(1);
#pragma unroll
      for (int mi = 0; mi < 4; ++mi) {
        int ra = t * 8192 + (mi * 16 + lcol) * 128;
        i32x4 lo = *(const i32x4*)&sL[ra + c0];
        i32x4 hi = *(const i32x4*)&sL[ra + c1];
        i32x8 af = (i32x8){lo[0], lo[1], lo[2], lo[3], hi[0], hi[1], hi[2], hi[3]};
#pragma unroll
        for (int ni = 0; ni < 4; ++ni)
          acc[mi][ni] = __builtin_amdgcn_mfma_scale_f32_16x16x128_f8f6f4(
              bv[ni], af, acc[mi][ni], 0, 0, 0, 0x7F, 0, 0x7F);
      }
      __builtin_amdgcn_s_setprio(0);
    }
    __syncthreads();   // staging dead; reuse sL[0,32K) as sO
  } else {
    // A-fragments direct from fragment-packed gF (2 KB contiguous per wave-instr).
    const unsigned char* aF = A + (long)slab * 524288 + net * 262144 + w * 32768 + lane * 32;
#pragma unroll
    for (int t = 0; t < 4; ++t) {
      i32x8 bv[4];
#pragma unroll
      for (int ni = 0; ni < 4; ++ni) {
        i32x4 lo = *(const i32x4*)(wbase + t * 65536 + ni * 2048);
        i32x4 hi = *(const i32x4*)(wbase + t * 65536 + ni * 2048 + 16);
        bv[ni] = (i32x8){lo[0], lo[1], lo[2], lo[3], hi[0], hi[1], hi[2], hi[3]};
      }
#pragma unroll
      for (int mi = 0; mi < 4; ++mi) {
        i32x4 lo = *(const i32x4*)(aF + t * 8192 + mi * 2048);
        i32x4 hi = *(const i32x4*)(aF + t * 8192 + mi * 2048 + 16);
        i32x8 af = (i32x8){lo[0], lo[1], lo[2], lo[3], hi[0], hi[1], hi[2], hi[3]};
        __builtin_amdgcn_s_setprio(1);
#pragma unroll
        for (int ni = 0; ni < 4; ++ni)
          acc[mi][ni] = __builtin_amdgcn_mfma_scale_f32_16x16x128_f8f6f4(
              bv[ni], af, acc[mi][ni], 0, 0, 0, 0x7F, 0, 0x7F);
        __builtin_amdgcn_s_setprio(0);
      }
    }
  }

  // ---- epilogue A: relu -> fp8 -> sO[j=w][64 r][16 dwords], dword-slot XOR (r&14) ----
#pragma unroll
  for (int ni = 0; ni < 4; ++ni) {
    int col = ni * 16 + quad * 4;
    float4 bw = *(const float4*)&lb[(net * 8 + w) * 512 + h0 + col];
    int sd = ni * 4 + quad;
#pragma unroll
    for (int mi = 0; mi < 4; ++mi) {
      int row = mi * 16 + lcol;
      float v0 = fmaxf(acc[mi][ni][0] * 0.0625f + bw.x, 0.f);
      float v1 = fmaxf(acc[mi][ni][1] * 0.0625f + bw.y, 0.f);
      float v2 = fmaxf(acc[mi][ni][2] * 0.0625f + bw.z, 0.f);
      float v3 = fmaxf(acc[mi][ni][3] * 0.0625f + bw.w, 0.f);
      unsigned d = __builtin_amdgcn_cvt_pk_fp8_f32(v0, v1, 0, false);
      d = __builtin_amdgcn_cvt_pk_fp8_f32(v2, v3, d, true);
      *(unsigned*)&sL[w * 4096 + row * 64 + ((sd ^ (row & 14)) << 2)] = d;
    }
  }
  __syncthreads();

  // ---- epilogue B: routed combine from LDS (packed f32x2 FMA); wave w = module i ----
  // gF write base: [slab][net][i=w][t=hb>>1][..]; per (r): + (r>>4)*2048 + (r&15)*32;
  // lane k5 = (hb&1)*2 + (sl>>2), byte (sl&3)*8. Full 128-B lines per store instr.
  const int poff = net ? poffA : poffC;
  unsigned char* gw = g + (long)slab * 524288 + net * 262144 + w * 32768 +
                      (hb >> 1) * 8192 + (((hb & 1) * 2 + (sl >> 2)) * 16) * 32 + (sl & 3) * 8;
#pragma unroll
  for (int k = 0; k < 8; ++k) {
    const int r = k * 8 + ln3;
    const float* pr = &probs[(long)(row0 + r) * 384 + poff + w * 8];
    float4 pA = *(const float4*)pr;
    float4 pB = *(const float4*)(pr + 4);
    float p8[8] = {pA.x, pA.y, pA.z, pA.w, pB.x, pB.y, pB.z, pB.w};
    f32x2 ga2[4] = {};
#pragma unroll
    for (int j = 0; j < 8; ++j) {
      uint2 o2 = *(const uint2*)&sL[j * 4096 + r * 64 + (((sl * 2) ^ (r & 14)) << 2)];
      f32x2 pw2 = {p8[j], p8[j]};
      ga2[0] += pw2 * __builtin_amdgcn_cvt_pk_f32_fp8(o2.x, false);
      ga2[1] += pw2 * __builtin_amdgcn_cvt_pk_f32_fp8(o2.x, true);
      ga2[2] += pw2 * __builtin_amdgcn_cvt_pk_f32_fp8(o2.y, false);
      ga2[3] += pw2 * __builtin_amdgcn_cvt_pk_f32_fp8(o2.y, true);
    }
    unsigned lo = __builtin_amdgcn_cvt_pk_fp8_f32(ga2[0][0], ga2[0][1], 0, false);
    lo = __builtin_amdgcn_cvt_pk_fp8_f32(ga2[1][0], ga2[1][1], lo, true);
    unsigned hi = __builtin_amdgcn_cvt_pk_fp8_f32(ga2[2][0], ga2[2][1], 0, false);
    hi = __builtin_amdgcn_cvt_pk_fp8_f32(ga2[3][0], ga2[3][1], hi, true);
    if (HEAD) {
      *(uint2*)&sL[32768 + w * 4096 + r * 64 + (((sl * 2) ^ (r & 14)) << 2)] =
          make_uint2(lo, hi);
    } else {
      *(uint2*)&gw[(r >> 4) * 2048 + (r & 15) * 32] = make_uint2(lo, hi);
    }
  }

  if (HEAD) {
    __syncthreads();
    const unsigned char* Wf = net ? Wfa : Wfc;
    const int ooff = net ? 0 : 19;
    const int mi = w & 3, kh = w >> 2;
    const int hrow = mi * 16 + lcol;
    f32x4 hacc[2] = {};
#pragma unroll
    for (int ks = 0; ks < 8; ++ks) {
      int j = kh * 4 + (ks >> 1);
      int u = (ks & 1) * 32 + quad * 8;
      int sd = u >> 2;
      long af = *(const long*)&sL[32768 + j * 4096 + hrow * 64 + ((sd ^ (hrow & 14)) << 2)];
      int kglob = hb * 512 + kh * 256 + ks * 32 + quad * 8;
      long bv0 = *(const long*)&Wf[(long)lcol * 4096 + kglob];
      hacc[0] = __builtin_amdgcn_mfma_f32_16x16x32_fp8_fp8(af, bv0, hacc[0], 0, 0, 0);
      if (net) {
        long bv1 = *(const long*)&Wf[(long)(16 + lcol) * 4096 + kglob];
        hacc[1] = __builtin_amdgcn_mfma_f32_16x16x32_fp8_fp8(af, bv1, hacc[1], 0, 0, 0);
      }
    }
    const int NOUTn = net ? NACT : 1;
#pragma unroll
    for (int ni = 0; ni < 2; ++ni) {
      if (ni == 1 && !net) break;
      int col = ni * 16 + lcol;
      if (col >= NOUTn) continue;
#pragma unroll
      for (int rr = 0; rr < 4; ++rr) {
        int row = row0 + mi * 16 + quad * 4 + rr;
        atomicAdd(&outp[(long)row * 20 + ooff + col], hacc[ni][rr] * 0.015625f);
      }
    }
  }
}

// ---------------- host ----------------

extern "C" void kernel_launch(void* const* d_in, const int* in_sizes, int n_in,
                              void* d_out, int out_size, void* d_ws, size_t ws_size,
                              hipStream_t stream) {
  const float* x        = (const float*)d_in[0];
  const int*   task_idx = (const int*)d_in[1];
  const float* enc_W1   = (const float*)d_in[2];
  const float* enc_b1   = (const float*)d_in[3];
  const float* enc_W2   = (const float*)d_in[4];
  const float* enc_b2   = (const float*)d_in[5];
  const float* task_emb = (const float*)d_in[6];
  const float* a_rW     = (const float*)d_in[7];
  const float* a_rb     = (const float*)d_in[8];
  const float* c_rW     = (const float*)d_in[9];
  const float* c_rb     = (const float*)d_in[10];
  const float* a_W      = (const float*)d_in[11];
  const float* a_b      = (const float*)d_in[12];
  const float* a_Wf     = (const float*)d_in[13];
  const float* a_bf     = (const float*)d_in[14];
  const float* c_W      = (const float*)d_in[15];
  const float* c_b      = (const float*)d_in[16];
  const float* c_Wf     = (const float*)d_in[17];
  const float* c_bf     = (const float*)d_in[18];
  const float* logstd   = (const float*)d_in[19];
  float* out = (float*)d_out;

  char* ws = (char*)d_ws;
  size_t off = 0;
  auto carve = [&](size_t bytes) {
    char* p = ws + off;
    off += (bytes + 255) & ~(size_t)255;
    return p;
  };
  // ---- fixed region ----
  unsigned char* W8 = (unsigned char*)carve((size_t)48 * 262144);   // frag-packed base weights
  unsigned char* W1T8 = (unsigned char*)carve((size_t)512 * 512);   // enc W1^T fp8 x16, K-pad 512
  unsigned char* W2T8 = (unsigned char*)carve((size_t)512 * 512);   // enc W2^T fp8 x16
  unsigned char* rWT8 = (unsigned char*)carve((size_t)384 * 512);   // routing W^T fp8 x16
  float* rball = (float*)carve(384 * 4);
  float* lb    = (float*)carve(3 * 16 * 512 * 4);                   // merged biases
  unsigned char* WfaT8 = (unsigned char*)carve((size_t)32 * 4096);  // head weights, perm-k
  unsigned char* WfcT8 = (unsigned char*)carve((size_t)32 * 4096);
  unsigned char* fs8 = (unsigned char*)carve((size_t)BSZ * HD);
  float* lgt   = (float*)carve((size_t)BSZ * 384 * 4);

  // ---- fp8 ping-pong region ([Bc, 8192] each; gF = 512 KB per 64-row slab) ----
  size_t remain = (ws_size > off) ? (ws_size - off) : 0;
  int Bc = 2048;
  for (int cand = BSZ; cand > 2048; cand >>= 1)
    if ((size_t)2 * cand * 8192 <= remain) { Bc = cand; break; }
  size_t half = (size_t)Bc * 8192;
  unsigned char* bufA8 = (unsigned char*)carve(half);
  unsigned char* bufB8 = (unsigned char*)carve(half);
  unsigned char* x8   = bufA8;   // [B,512] fp8, dead after enc1
  unsigned char* h18  = bufB8;   // [B,512] fp8, dead after enc2
  unsigned char* rel8 = bufA8;   // [B,512] fp8, dead after routing

  dim3 tb(32, 8);

  // ---- prep ----
  k_cvt_pad8<<<(int)(((long)BSZ * HD + 255) / 256), 256, 0, stream>>>(x, x8);
  k_packT8<<<dim3(16, 16, 1), tb, 0, stream>>>(enc_W1, W1T8, OBSN, 512, 512, 0, 0, 16.f);
  k_packT8<<<dim3(16, 16, 1), tb, 0, stream>>>(enc_W2, W2T8, 512, 512, 512, 0, 0, 16.f);
  k_packT8<<<dim3(2, 16, 3),  tb, 0, stream>>>(a_rW, rWT8,             512, 64, 512, 512 * 64, 64 * 512, 16.f);
  k_packT8<<<dim3(2, 16, 3),  tb, 0, stream>>>(c_rW, rWT8 + 192 * 512, 512, 64, 512, 512 * 64, 64 * 512, 16.f);
  k_packwF<<<dim3(4, 4, 48), 256, 0, stream>>>(a_W, c_W, W8);
  k_packmisc<<<610, 256, 0, stream>>>(a_b, c_b, a_Wf, c_Wf, a_rb, c_rb,
                                      lb, WfaT8, WfcT8, rball);
  k_initout2<<<(int)(((long)BSZ * 20 + 255) / 256), 256, 0, stream>>>(a_bf, c_bf, logstd, out);

  const int GY = BSZ / 128;
  // ---- encoder + routing (proven 3-dispatch chain) ----
  k_gemm8<1><<<4 * GY, 256, 0, stream>>>(x8, W1T8, h18, enc_b1, 512, 512, 512, 512,
                                         4, GY, nullptr, nullptr, nullptr);
  k_gemm8<5><<<4 * GY, 256, 0, stream>>>(h18, W2T8, fs8, enc_b2, 512, 512, 512, 512,
                                         4, GY, task_idx, task_emb, rel8);
  k_gemm8<4><<<3 * GY, 256, 0, stream>>>(rel8, rWT8, lgt, rball, 384, 512, 512, 384,
                                         3, GY, nullptr, nullptr, nullptr);

  // ---- base nets: fused GEMM+combine (fragment-packed g), layer 3 fuses heads ----
  const size_t wlz = (size_t)16 * 262144;
  for (int c0 = 0; c0 < BSZ; c0 += Bc) {
    const unsigned char* fs_c = fs8 + (long)c0 * 512;
    const float* pr_c  = lgt + (long)c0 * 384;
    float*       out_c = out + (long)c0 * 20;
    unsigned char* bufA_c = bufA8 + (long)c0 * 8192;
    unsigned char* bufB_c = bufB8 + (long)c0 * 8192;
    const int gyF = Bc / 64;

    k_gemmF<0, 0><<<16 * gyF, 512, 0, stream>>>(fs_c, W8, lb, pr_c, bufA_c, gyF, 192, 0,
                                                nullptr, nullptr, nullptr);
    k_gemmF<1, 0><<<16 * gyF, 512, 0, stream>>>(bufA_c, W8 + wlz, lb + 8192, pr_c, bufB_c,
                                                gyF, 192 + 64, 64, nullptr, nullptr, nullptr);
    k_gemmF<1, 1><<<16 * gyF, 512, 0, stream>>>(bufB_c, W8 + 2 * wlz, lb + 16384, pr_c, bufA_c,
                                                gyF, 192 + 128, 128, WfcT8, WfaT8, out_c);
  }
}

// Round 14
// 798.795 us; speedup vs baseline: 1.0816x; 1.0816x over previous
//
#include <hip/hip_runtime.h>
#include <hip/hip_bf16.h>

typedef float f32x4 __attribute__((ext_vector_type(4)));
typedef float f32x2 __attribute__((ext_vector_type(2)));
typedef int   i32x4 __attribute__((ext_vector_type(4)));
typedef int   i32x8 __attribute__((ext_vector_type(8)));

#define LOG_SQRT_2PI 0.91893853320467274f

static constexpr int BSZ  = 16384;
static constexpr int OBSN = 376;
static constexpr int HD   = 512;
static constexpr int NACT = 17;

__device__ __forceinline__ unsigned char f2fp8(float v) {
  return (unsigned char)(__builtin_amdgcn_cvt_pk_fp8_f32(v, v, 0, false) & 0xFF);
}

__device__ __forceinline__ void gl16(const unsigned char* g, unsigned char* l) {
  __builtin_amdgcn_global_load_lds((const __attribute__((address_space(1))) void*)g,
                                   (__attribute__((address_space(3))) void*)l, 16, 0, 0);
}

// XCD-aware tile remap. Requires grid % 8 == 0.
__device__ __forceinline__ void xcd_map(int id, int gx, int gy, int& bx, int& by, int& bz) {
  int p = id & 7, l = id >> 3;
  bx = l % gx;
  int g = (l / gx) * 8 + p;
  by = g % gy;
  bz = g / gy;
}

// ---------------- prep kernels ----------------

// x [B,376] f32 -> [B,512] fp8 (zero pad)
__global__ void k_cvt_pad8(const float* __restrict__ src, unsigned char* __restrict__ dst) {
  long i = (long)blockIdx.x * 256 + threadIdx.x;
  if (i >= (long)BSZ * HD) return;
  long r = i >> 9;
  int  c = (int)(i & 511);
  dst[i] = f2fp8(c < OBSN ? src[r * OBSN + c] : 0.f);
}

// dst[n][k] = fp8(scale * src[k][n]); zero for k >= K. batched via blockIdx.z.
__global__ void k_packT8(const float* __restrict__ src, unsigned char* __restrict__ dst,
                         int K, int N, int Kpad, long sstride, long dstride, float scale) {
  __shared__ float t[32][33];
  src += (long)blockIdx.z * sstride;
  dst += (long)blockIdx.z * dstride;
  int k0 = blockIdx.y * 32, n0 = blockIdx.x * 32;
#pragma unroll
  for (int ii = 0; ii < 4; ++ii) {
    int i = ii * 8 + threadIdx.y;
    int k = k0 + i, n = n0 + threadIdx.x;
    t[i][threadIdx.x] = (k < K && n < N) ? src[(long)k * N + n] : 0.f;
  }
  __syncthreads();
#pragma unroll
  for (int ii = 0; ii < 4; ++ii) {
    int i = ii * 8 + threadIdx.y;
    int n = n0 + i, k = k0 + threadIdx.x;
    if (n < N && k < Kpad) dst[(long)n * Kpad + k] = f2fp8(scale * t[threadIdx.x][i]);
  }
}

// base-net weights -> FRAGMENT-PACKED fp8 x16, via LDS transpose (coalesced reads,
// contiguous 32 B fragment writes). Bit-exact verified.
__global__ void k_packwF(const float* __restrict__ aW, const float* __restrict__ cW,
                         unsigned char* __restrict__ dst) {
  __shared__ unsigned char sT[128 * 144];
  const int tid = threadIdx.x;            // 256
  const int z = blockIdx.z;               // 0..47
  const int t = blockIdx.y;               // 0..3
  const int ng = blockIdx.x;              // 0..3
  const int layer = z >> 4, zz = z & 15, net = zz >> 3, m = zz & 7;
  const float* src = (net ? aW : cW) + (long)(layer * 8 + m) * 262144;
#pragma unroll
  for (int i = 0; i < 64; ++i) {
    int lin = i * 256 + tid;
    int kl = lin >> 7, nl = lin & 127;
    float v = src[(long)(t * 128 + kl) * 512 + ng * 128 + nl];
    sT[nl * 144 + kl] = f2fp8(16.f * v);
  }
  __syncthreads();
#pragma unroll
  for (int f = 0; f < 2; ++f) {
    int fid = f * 256 + tid;
    int lane = fid & 63, nb_l = fid >> 6;
    int n_l = nb_l * 16 + (lane & 15);
    int klo = ((lane >> 4) & 3) * 32;
    uint4 lo = *(const uint4*)&sT[n_l * 144 + klo];
    uint4 hi = *(const uint4*)&sT[n_l * 144 + klo + 16];
    int nb = ng * 8 + nb_l;
    unsigned char* d = dst + ((((long)z * 4 + t) * 32 + nb) * 64 + lane) * 32;
    *(uint4*)d = lo;
    *(uint4*)(d + 16) = hi;
  }
}

// merged small packs: lb (merged biases), head weights (permuted-k), routing bias
__global__ void k_packmisc(const float* __restrict__ a_b, const float* __restrict__ c_b,
                           const float* __restrict__ aWf, const float* __restrict__ cWf,
                           const float* __restrict__ a_rb, const float* __restrict__ c_rb,
                           float* __restrict__ lb, unsigned char* __restrict__ dsta,
                           unsigned char* __restrict__ dstc, float* __restrict__ rb) {
  int i = blockIdx.x * 256 + threadIdx.x;
  if (i < 24576) {
    int layer = i >> 13, zz = (i >> 9) & 15, n = i & 511;
    int net = zz >> 3, m = zz & 7;
    lb[i] = (net ? a_b : c_b)[(layer * 8 + m) * 512 + n];
  } else if (i < 24576 + 131072) {
    int j = i - 24576;
    int n = j >> 12, kn = j & 4095;
    int hb = kn >> 9, rem = kn & 511, m = rem >> 6, u = kn & 63;
    int ko = m * 512 + hb * 64 + u;
    dsta[j] = (n < NACT) ? f2fp8(64.f * aWf[(long)ko * NACT + n]) : (unsigned char)0;
    dstc[j] = (n < 1)    ? f2fp8(64.f * cWf[ko])                  : (unsigned char)0;
  } else if (i < 24576 + 131072 + 384) {
    int j = i - 24576 - 131072;
    rb[j] = (j < 192) ? a_rb[j] : c_rb[j - 192];
  }
}

// out init: bias sums for actor/critic heads + logstd constants (cols 17/18).
__global__ void k_initout2(const float* __restrict__ a_bf, const float* __restrict__ c_bf,
                           const float* __restrict__ ls, float* __restrict__ out) {
  long i = (long)blockIdx.x * 256 + threadIdx.x;   // BSZ*20
  if (i >= (long)BSZ * 20) return;
  int o = (int)(i % 20);
  float v = 0.f;
  if (o < NACT) {
    for (int m = 0; m < 8; ++m) v += a_bf[m * NACT + o];
  } else if (o == 19) {
    for (int m = 0; m < 8; ++m) v += c_bf[m];
  } else if (o == 17) {
    for (int a = 0; a < NACT; ++a) v += -ls[a] - LOG_SQRT_2PI;
  } else {
    for (int a = 0; a < NACT; ++a) v += 0.5f + LOG_SQRT_2PI + ls[a];
  }
  out[i] = v;
}

// ---------------- unified MX fp8 GEMM (LDS path): encoder / routing ----------------
// OP: 1 = tanh -> fp8 (encoder-1); 5 = tanh->fp8 AND fp8(relu(tanh*temb)) (encoder-2)
//     4 = softmax over col-octets -> f32 (routing)
template <int OP>
__global__ __launch_bounds__(256, 4)
void k_gemm8(const unsigned char* __restrict__ A, const unsigned char* __restrict__ Bt,
             void* __restrict__ Cv, const float* __restrict__ bias,
             int N, int K, int lda, int ldc, int gx, int gy,
             const int* __restrict__ tidx, const float* __restrict__ temb,
             unsigned char* __restrict__ out2) {
  __shared__ alignas(16) unsigned char sA[128 * 128];
  __shared__ alignas(16) unsigned char sB[128 * 128];
  int bx, by, z;
  xcd_map(blockIdx.x, gx, gy, bx, by, z);
  const int tid  = threadIdx.x;
  const int wave = tid >> 6, lane = tid & 63;
  const int wr = (wave >> 1) * 64, wc = (wave & 1) * 64;
  const int row0 = by * 128, col0 = bx * 128;
  const int lcol = lane & 15, quad = lane >> 4;
  const int sw7 = lcol & 7;
  const int c0 = ((2 * quad)     ^ sw7) * 16;
  const int c1 = ((2 * quad + 1) ^ sw7) * 16;
  const int raA0 = (wr + lcol) * 128 + c0, raA1 = (wr + lcol) * 128 + c1;
  const int rbB0 = (wc + lcol) * 128 + c0, rbB1 = (wc + lcol) * 128 + c1;
  int aOff[4], bOff[4];
#pragma unroll
  for (int i = 0; i < 4; ++i) {
    int u = i * 256 + tid;
    int r = u >> 3, gc = (u & 7) ^ (r & 7);
    aOff[i] = (row0 + r) * lda + gc * 16;
    bOff[i] = (col0 + r) * K + gc * 16;
  }

  f32x4 acc[4][4] = {};

  for (int kt = 0; kt < K; kt += 128) {
#pragma unroll
    for (int i = 0; i < 4; ++i) gl16(A + aOff[i] + kt, &sA[i * 4096 + tid * 16]);
#pragma unroll
    for (int i = 0; i < 4; ++i) gl16(Bt + bOff[i] + kt, &sB[i * 4096 + tid * 16]);
    __syncthreads();
    i32x8 bv[4];
#pragma unroll
    for (int ni = 0; ni < 4; ++ni) {
      i32x4 blo = *(const i32x4*)&sB[rbB0 + ni * 2048];
      i32x4 bhi = *(const i32x4*)&sB[rbB1 + ni * 2048];
      bv[ni] = (i32x8){blo[0], blo[1], blo[2], blo[3], bhi[0], bhi[1], bhi[2], bhi[3]};
    }
#pragma unroll
    for (int mi = 0; mi < 4; ++mi) {
      i32x4 alo = *(const i32x4*)&sA[raA0 + mi * 2048];
      i32x4 ahi = *(const i32x4*)&sA[raA1 + mi * 2048];
      i32x8 af = (i32x8){alo[0], alo[1], alo[2], alo[3], ahi[0], ahi[1], ahi[2], ahi[3]};
#pragma unroll
      for (int ni = 0; ni < 4; ++ni)
        acc[mi][ni] = __builtin_amdgcn_mfma_scale_f32_16x16x128_f8f6f4(
            bv[ni], af, acc[mi][ni], 0, 0, 0, 0x7F, 0, 0x7F);
    }
    __syncthreads();
  }

#pragma unroll
  for (int ni = 0; ni < 4; ++ni) {
    int colb = col0 + wc + ni * 16 + quad * 4;
    if (colb >= N) continue;
    float4 bw = *(const float4*)&bias[colb];
#pragma unroll
    for (int mi = 0; mi < 4; ++mi) {
      int rowg = row0 + wr + mi * 16 + lcol;
      float v0 = acc[mi][ni][0] * 0.0625f + bw.x;
      float v1 = acc[mi][ni][1] * 0.0625f + bw.y;
      float v2 = acc[mi][ni][2] * 0.0625f + bw.z;
      float v3 = acc[mi][ni][3] * 0.0625f + bw.w;
      long idx = (long)rowg * ldc + colb;
      if (OP == 1) {
        float t0 = tanhf(v0), t1 = tanhf(v1), t2 = tanhf(v2), t3 = tanhf(v3);
        unsigned d = __builtin_amdgcn_cvt_pk_fp8_f32(t0, t1, 0, false);
        d = __builtin_amdgcn_cvt_pk_fp8_f32(t2, t3, d, true);
        *(unsigned*)&((unsigned char*)Cv)[idx] = d;
      } else if (OP == 5) {
        float t0 = tanhf(v0), t1 = tanhf(v1), t2 = tanhf(v2), t3 = tanhf(v3);
        unsigned d = __builtin_amdgcn_cvt_pk_fp8_f32(t0, t1, 0, false);
        d = __builtin_amdgcn_cvt_pk_fp8_f32(t2, t3, d, true);
        *(unsigned*)&((unsigned char*)Cv)[idx] = d;
        int tk = tidx[rowg];
        float4 te = *(const float4*)&temb[(long)tk * HD + colb];
        unsigned e = __builtin_amdgcn_cvt_pk_fp8_f32(fmaxf(t0 * te.x, 0.f), fmaxf(t1 * te.y, 0.f), 0, false);
        e = __builtin_amdgcn_cvt_pk_fp8_f32(fmaxf(t2 * te.z, 0.f), fmaxf(t3 * te.w, 0.f), e, true);
        *(unsigned*)&out2[idx] = e;
      } else if (OP == 4) {
        float mx = fmaxf(fmaxf(v0, v1), fmaxf(v2, v3));
        mx = fmaxf(mx, __shfl_xor(mx, 16));
        float e0 = __expf(v0 - mx), e1 = __expf(v1 - mx), e2 = __expf(v2 - mx), e3 = __expf(v3 - mx);
        float s = e0 + e1 + e2 + e3;
        s += __shfl_xor(s, 16);
        float inv = 1.f / s;
        *(float4*)&((float*)Cv)[idx] = make_float4(e0 * inv, e1 * inv, e2 * inv, e3 * inv);
      }
    }
  }
}

// ---------------- FUSED base-net layer: GEMM (8 modules) + routed combine (+head) ----
// AMODE0 (layer 1): 64-row slab, proven R12 structure, LDS 32 KB.
// AMODE1 (layers 2/3): 32-row slab, acc[2][4], 4 KB/wave staging (32 KB total) ->
// LDS 32 KB incl. sO (16 KB) + sG (16 KB, HEAD); __launch_bounds__(512,6) targets
// 3 blocks/CU = 24 waves (vs 16) to hide the per-tile vmcnt(0) latency.
template <int AMODE, int HEAD>
__global__ __launch_bounds__(512, AMODE ? 6 : 4)
void k_gemmF(const unsigned char* __restrict__ A, const unsigned char* __restrict__ Wp,
             const float* __restrict__ lb, const float* __restrict__ probs,
             unsigned char* __restrict__ g, int gy, int poffC, int poffA,
             const unsigned char* __restrict__ Wfc, const unsigned char* __restrict__ Wfa,
             float* __restrict__ outp) {
  __shared__ alignas(16) unsigned char sL[32768];
  int hb, slab, net;
  xcd_map(blockIdx.x, 8, gy, hb, slab, net);
  const int tid = threadIdx.x;
  const int w = tid >> 6, lane = tid & 63;
  const int lcol = lane & 15, quad = lane >> 4;
  const int ln3 = lane >> 3, sl = lane & 7;
  const int row0 = slab * (AMODE ? 32 : 64);
  const int h0 = hb * 64;
  const int sw7 = lcol & 7;
  const int c0 = ((2 * quad)     ^ sw7) * 16;
  const int c1 = ((2 * quad + 1) ^ sw7) * 16;
  const int ch = sl ^ ln3;
  const unsigned char* wbase =
      Wp + (((long)(net * 8 + w) * 4 * 32 + hb * 4) * 64 + lane) * 32;
  const int poff = net ? poffA : poffC;

  if (AMODE == 0) {
    f32x4 acc[4][4] = {};
#pragma unroll
    for (int i = 0; i < 4; ++i) {
      int vb = w * 4 + i;
      int rr = (vb & 7) * 8 + ln3;
      gl16(A + (row0 + rr) * 512 + (vb >> 3) * 128 + ch * 16, &sL[(vb * 64 + lane) * 16]);
    }
    __syncthreads();
#pragma unroll
    for (int t = 0; t < 4; ++t) {
      i32x8 bv[4];
#pragma unroll
      for (int ni = 0; ni < 4; ++ni) {
        i32x4 lo = *(const i32x4*)(wbase + t * 65536 + ni * 2048);
        i32x4 hi = *(const i32x4*)(wbase + t * 65536 + ni * 2048 + 16);
        bv[ni] = (i32x8){lo[0], lo[1], lo[2], lo[3], hi[0], hi[1], hi[2], hi[3]};
      }
      __builtin_amdgcn_s_setprio(1);
#pragma unroll
      for (int mi = 0; mi < 4; ++mi) {
        int ra = t * 8192 + (mi * 16 + lcol) * 128;
        i32x4 lo = *(const i32x4*)&sL[ra + c0];
        i32x4 hi = *(const i32x4*)&sL[ra + c1];
        i32x8 af = (i32x8){lo[0], lo[1], lo[2], lo[3], hi[0], hi[1], hi[2], hi[3]};
#pragma unroll
        for (int ni = 0; ni < 4; ++ni)
          acc[mi][ni] = __builtin_amdgcn_mfma_scale_f32_16x16x128_f8f6f4(
              bv[ni], af, acc[mi][ni], 0, 0, 0, 0x7F, 0, 0x7F);
      }
      __builtin_amdgcn_s_setprio(0);
    }
    __syncthreads();   // staging dead; reuse sL[0,32K) as sO

    // relu -> fp8 -> sO[j=w][64 r][16 dwords], dword-slot XOR (r&14)
#pragma unroll
    for (int ni = 0; ni < 4; ++ni) {
      int col = ni * 16 + quad * 4;
      float4 bw = *(const float4*)&lb[(net * 8 + w) * 512 + h0 + col];
      int sd = ni * 4 + quad;
#pragma unroll
      for (int mi = 0; mi < 4; ++mi) {
        int row = mi * 16 + lcol;
        float v0 = fmaxf(acc[mi][ni][0] * 0.0625f + bw.x, 0.f);
        float v1 = fmaxf(acc[mi][ni][1] * 0.0625f + bw.y, 0.f);
        float v2 = fmaxf(acc[mi][ni][2] * 0.0625f + bw.z, 0.f);
        float v3 = fmaxf(acc[mi][ni][3] * 0.0625f + bw.w, 0.f);
        unsigned d = __builtin_amdgcn_cvt_pk_fp8_f32(v0, v1, 0, false);
        d = __builtin_amdgcn_cvt_pk_fp8_f32(v2, v3, d, true);
        *(unsigned*)&sL[w * 4096 + row * 64 + ((sd ^ (row & 14)) << 2)] = d;
      }
    }
    __syncthreads();

    // routed combine from LDS; wave w = module i
#pragma unroll
    for (int k = 0; k < 8; ++k) {
      const int r = k * 8 + ln3;
      const float* pr = &probs[(long)(row0 + r) * 384 + poff + w * 8];
      float4 pA = *(const float4*)pr;
      float4 pB = *(const float4*)(pr + 4);
      float p8[8] = {pA.x, pA.y, pA.z, pA.w, pB.x, pB.y, pB.z, pB.w};
      f32x2 ga2[4] = {};
#pragma unroll
      for (int j = 0; j < 8; ++j) {
        uint2 o2 = *(const uint2*)&sL[j * 4096 + r * 64 + (((sl * 2) ^ (r & 14)) << 2)];
        f32x2 pw2 = {p8[j], p8[j]};
        ga2[0] += pw2 * __builtin_amdgcn_cvt_pk_f32_fp8(o2.x, false);
        ga2[1] += pw2 * __builtin_amdgcn_cvt_pk_f32_fp8(o2.x, true);
        ga2[2] += pw2 * __builtin_amdgcn_cvt_pk_f32_fp8(o2.y, false);
        ga2[3] += pw2 * __builtin_amdgcn_cvt_pk_f32_fp8(o2.y, true);
      }
      unsigned lo = __builtin_amdgcn_cvt_pk_fp8_f32(ga2[0][0], ga2[0][1], 0, false);
      lo = __builtin_amdgcn_cvt_pk_fp8_f32(ga2[1][0], ga2[1][1], lo, true);
      unsigned hi = __builtin_amdgcn_cvt_pk_fp8_f32(ga2[2][0], ga2[2][1], 0, false);
      hi = __builtin_amdgcn_cvt_pk_fp8_f32(ga2[3][0], ga2[3][1], hi, true);
      *(uint2*)&g[(long)(row0 + r) * 8192 + net * 4096 + w * 512 + h0 + sl * 8] =
          make_uint2(lo, hi);
    }
    return;
  }

  // ================= AMODE 1: 32-row slab =================
  f32x4 acc[2][4] = {};
  {
    const unsigned char* abase = A + (long)(row0 + ln3) * 8192 + net * 4096 +
                                 w * 512 + ch * 16;
    unsigned char* dbase = &sL[w * 4096 + lane * 16];
#pragma unroll 1
    for (int t = 0; t < 4; ++t) {
#pragma unroll
      for (int i = 0; i < 4; ++i)
        gl16(abase + i * 8 * 8192 + t * 128, dbase + i * 1024);
      asm volatile("s_waitcnt vmcnt(0)" ::: "memory");
      __builtin_amdgcn_sched_barrier(0);
      i32x8 af[2];
#pragma unroll
      for (int mi = 0; mi < 2; ++mi) {
        int ra = w * 4096 + (mi * 16 + lcol) * 128;
        i32x4 lo = *(const i32x4*)&sL[ra + c0];
        i32x4 hi = *(const i32x4*)&sL[ra + c1];
        af[mi] = (i32x8){lo[0], lo[1], lo[2], lo[3], hi[0], hi[1], hi[2], hi[3]};
      }
      __builtin_amdgcn_s_setprio(1);
#pragma unroll
      for (int ni = 0; ni < 4; ++ni) {
        i32x4 lo = *(const i32x4*)(wbase + t * 65536 + ni * 2048);
        i32x4 hi = *(const i32x4*)(wbase + t * 65536 + ni * 2048 + 16);
        i32x8 bv = (i32x8){lo[0], lo[1], lo[2], lo[3], hi[0], hi[1], hi[2], hi[3]};
        acc[0][ni] = __builtin_amdgcn_mfma_scale_f32_16x16x128_f8f6f4(
            bv, af[0], acc[0][ni], 0, 0, 0, 0x7F, 0, 0x7F);
        acc[1][ni] = __builtin_amdgcn_mfma_scale_f32_16x16x128_f8f6f4(
            bv, af[1], acc[1][ni], 0, 0, 0, 0x7F, 0, 0x7F);
      }
      __builtin_amdgcn_s_setprio(0);
    }
  }
  __syncthreads();   // staging dead; reuse sL[0,16K) as sO, [16K,32K) as sG (HEAD)

  // ---- epilogue A: relu -> fp8 -> sO[j=w][32 r][16 dwords], dword-slot XOR (r&14) ----
#pragma unroll
  for (int ni = 0; ni < 4; ++ni) {
    int col = ni * 16 + quad * 4;
    float4 bw = *(const float4*)&lb[(net * 8 + w) * 512 + h0 + col];
    int sd = ni * 4 + quad;
#pragma unroll
    for (int mi = 0; mi < 2; ++mi) {
      int row = mi * 16 + lcol;
      float v0 = fmaxf(acc[mi][ni][0] * 0.0625f + bw.x, 0.f);
      float v1 = fmaxf(acc[mi][ni][1] * 0.0625f + bw.y, 0.f);
      float v2 = fmaxf(acc[mi][ni][2] * 0.0625f + bw.z, 0.f);
      float v3 = fmaxf(acc[mi][ni][3] * 0.0625f + bw.w, 0.f);
      unsigned d = __builtin_amdgcn_cvt_pk_fp8_f32(v0, v1, 0, false);
      d = __builtin_amdgcn_cvt_pk_fp8_f32(v2, v3, d, true);
      *(unsigned*)&sL[w * 2048 + row * 64 + ((sd ^ (row & 14)) << 2)] = d;
    }
  }
  __syncthreads();

  // ---- epilogue B: routed combine from LDS; wave w = module i, rows 0..31 ----
#pragma unroll
  for (int k = 0; k < 4; ++k) {
    const int r = k * 8 + ln3;
    const float* pr = &probs[(long)(row0 + r) * 384 + poff + w * 8];
    float4 pA = *(const float4*)pr;
    float4 pB = *(const float4*)(pr + 4);
    float p8[8] = {pA.x, pA.y, pA.z, pA.w, pB.x, pB.y, pB.z, pB.w};
    f32x2 ga2[4] = {};
#pragma unroll
    for (int j = 0; j < 8; ++j) {
      uint2 o2 = *(const uint2*)&sL[j * 2048 + r * 64 + (((sl * 2) ^ (r & 14)) << 2)];
      f32x2 pw2 = {p8[j], p8[j]};
      ga2[0] += pw2 * __builtin_amdgcn_cvt_pk_f32_fp8(o2.x, false);
      ga2[1] += pw2 * __builtin_amdgcn_cvt_pk_f32_fp8(o2.x, true);
      ga2[2] += pw2 * __builtin_amdgcn_cvt_pk_f32_fp8(o2.y, false);
      ga2[3] += pw2 * __builtin_amdgcn_cvt_pk_f32_fp8(o2.y, true);
    }
    unsigned lo = __builtin_amdgcn_cvt_pk_fp8_f32(ga2[0][0], ga2[0][1], 0, false);
    lo = __builtin_amdgcn_cvt_pk_fp8_f32(ga2[1][0], ga2[1][1], lo, true);
    unsigned hi = __builtin_amdgcn_cvt_pk_fp8_f32(ga2[2][0], ga2[2][1], 0, false);
    hi = __builtin_amdgcn_cvt_pk_fp8_f32(ga2[3][0], ga2[3][1], hi, true);
    if (HEAD) {
      *(uint2*)&sL[16384 + w * 2048 + r * 64 + (((sl * 2) ^ (r & 14)) << 2)] =
          make_uint2(lo, hi);
    } else {
      *(uint2*)&g[(long)(row0 + r) * 8192 + net * 4096 + w * 512 + h0 + sl * 8] =
          make_uint2(lo, hi);
    }
  }

  if (HEAD) {
    __syncthreads();
    // head over this block's 64-h slice; 8 waves = (mi 0..1) x (kq 0..3).
    const unsigned char* Wf = net ? Wfa : Wfc;
    const int ooff = net ? 0 : 19;
    const int mi = w & 1, kq = w >> 1;
    const int hrow = mi * 16 + lcol;
    f32x4 hacc[2] = {};
#pragma unroll
    for (int ks = 0; ks < 4; ++ks) {
      int j = kq * 2 + (ks >> 1);
      int u = (ks & 1) * 32 + quad * 8;
      int sd = u >> 2;
      long af = *(const long*)&sL[16384 + j * 2048 + hrow * 64 + ((sd ^ (hrow & 14)) << 2)];
      int kglob = hb * 512 + j * 64 + u;
      long bv0 = *(const long*)&Wf[(long)lcol * 4096 + kglob];
      hacc[0] = __builtin_amdgcn_mfma_f32_16x16x32_fp8_fp8(af, bv0, hacc[0], 0, 0, 0);
      if (net) {
        long bv1 = *(const long*)&Wf[(long)(16 + lcol) * 4096 + kglob];
        hacc[1] = __builtin_amdgcn_mfma_f32_16x16x32_fp8_fp8(af, bv1, hacc[1], 0, 0, 0);
      }
    }
    const int NOUTn = net ? NACT : 1;
#pragma unroll
    for (int ni = 0; ni < 2; ++ni) {
      if (ni == 1 && !net) break;
      int col = ni * 16 + lcol;
      if (col >= NOUTn) continue;
#pragma unroll
      for (int rr = 0; rr < 4; ++rr) {
        int row = row0 + mi * 16 + quad * 4 + rr;
        atomicAdd(&outp[(long)row * 20 + ooff + col], hacc[ni][rr] * 0.015625f);
      }
    }
  }
}

// ---------------- host ----------------

extern "C" void kernel_launch(void* const* d_in, const int* in_sizes, int n_in,
                              void* d_out, int out_size, void* d_ws, size_t ws_size,
                              hipStream_t stream) {
  const float* x        = (const float*)d_in[0];
  const int*   task_idx = (const int*)d_in[1];
  const float* enc_W1   = (const float*)d_in[2];
  const float* enc_b1   = (const float*)d_in[3];
  const float* enc_W2   = (const float*)d_in[4];
  const float* enc_b2   = (const float*)d_in[5];
  const float* task_emb = (const float*)d_in[6];
  const float* a_rW     = (const float*)d_in[7];
  const float* a_rb     = (const float*)d_in[8];
  const float* c_rW     = (const float*)d_in[9];
  const float* c_rb     = (const float*)d_in[10];
  const float* a_W      = (const float*)d_in[11];
  const float* a_b      = (const float*)d_in[12];
  const float* a_Wf     = (const float*)d_in[13];
  const float* a_bf     = (const float*)d_in[14];
  const float* c_W      = (const float*)d_in[15];
  const float* c_b      = (const float*)d_in[16];
  const float* c_Wf     = (const float*)d_in[17];
  const float* c_bf     = (const float*)d_in[18];
  const float* logstd   = (const float*)d_in[19];
  float* out = (float*)d_out;

  char* ws = (char*)d_ws;
  size_t off = 0;
  auto carve = [&](size_t bytes) {
    char* p = ws + off;
    off += (bytes + 255) & ~(size_t)255;
    return p;
  };
  // ---- fixed region ----
  unsigned char* W8 = (unsigned char*)carve((size_t)48 * 262144);   // frag-packed base weights
  unsigned char* W1T8 = (unsigned char*)carve((size_t)512 * 512);   // enc W1^T fp8 x16, K-pad 512
  unsigned char* W2T8 = (unsigned char*)carve((size_t)512 * 512);   // enc W2^T fp8 x16
  unsigned char* rWT8 = (unsigned char*)carve((size_t)384 * 512);   // routing W^T fp8 x16
  float* rball = (float*)carve(384 * 4);
  float* lb    = (float*)carve(3 * 16 * 512 * 4);                   // merged biases
  unsigned char* WfaT8 = (unsigned char*)carve((size_t)32 * 4096);  // head weights, perm-k
  unsigned char* WfcT8 = (unsigned char*)carve((size_t)32 * 4096);
  unsigned char* fs8 = (unsigned char*)carve((size_t)BSZ * HD);
  float* lgt   = (float*)carve((size_t)BSZ * 384 * 4);

  // ---- fp8 ping-pong region ([Bc, 8192] each) ----
  size_t remain = (ws_size > off) ? (ws_size - off) : 0;
  int Bc = 2048;
  for (int cand = BSZ; cand > 2048; cand >>= 1)
    if ((size_t)2 * cand * 8192 <= remain) { Bc = cand; break; }
  size_t half = (size_t)Bc * 8192;
  unsigned char* bufA8 = (unsigned char*)carve(half);
  unsigned char* bufB8 = (unsigned char*)carve(half);
  unsigned char* x8   = bufA8;   // [B,512] fp8, dead after enc1
  unsigned char* h18  = bufB8;   // [B,512] fp8, dead after enc2
  unsigned char* rel8 = bufA8;   // [B,512] fp8, dead after routing

  dim3 tb(32, 8);

  // ---- prep ----
  k_cvt_pad8<<<(int)(((long)BSZ * HD + 255) / 256), 256, 0, stream>>>(x, x8);
  k_packT8<<<dim3(16, 16, 1), tb, 0, stream>>>(enc_W1, W1T8, OBSN, 512, 512, 0, 0, 16.f);
  k_packT8<<<dim3(16, 16, 1), tb, 0, stream>>>(enc_W2, W2T8, 512, 512, 512, 0, 0, 16.f);
  k_packT8<<<dim3(2, 16, 3),  tb, 0, stream>>>(a_rW, rWT8,             512, 64, 512, 512 * 64, 64 * 512, 16.f);
  k_packT8<<<dim3(2, 16, 3),  tb, 0, stream>>>(c_rW, rWT8 + 192 * 512, 512, 64, 512, 512 * 64, 64 * 512, 16.f);
  k_packwF<<<dim3(4, 4, 48), 256, 0, stream>>>(a_W, c_W, W8);
  k_packmisc<<<610, 256, 0, stream>>>(a_b, c_b, a_Wf, c_Wf, a_rb, c_rb,
                                      lb, WfaT8, WfcT8, rball);
  k_initout2<<<(int)(((long)BSZ * 20 + 255) / 256), 256, 0, stream>>>(a_bf, c_bf, logstd, out);

  const int GY = BSZ / 128;
  // ---- encoder + routing (proven 3-dispatch chain) ----
  k_gemm8<1><<<4 * GY, 256, 0, stream>>>(x8, W1T8, h18, enc_b1, 512, 512, 512, 512,
                                         4, GY, nullptr, nullptr, nullptr);
  k_gemm8<5><<<4 * GY, 256, 0, stream>>>(h18, W2T8, fs8, enc_b2, 512, 512, 512, 512,
                                         4, GY, task_idx, task_emb, rel8);
  k_gemm8<4><<<3 * GY, 256, 0, stream>>>(rel8, rWT8, lgt, rball, 384, 512, 512, 384,
                                         3, GY, nullptr, nullptr, nullptr);

  // ---- base nets: fused GEMM+combine, layer 3 fuses heads ----
  const size_t wlz = (size_t)16 * 262144;
  for (int c0 = 0; c0 < BSZ; c0 += Bc) {
    const unsigned char* fs_c = fs8 + (long)c0 * 512;
    const float* pr_c  = lgt + (long)c0 * 384;
    float*       out_c = out + (long)c0 * 20;
    const int gy1 = Bc / 64, gy2 = Bc / 32;

    k_gemmF<0, 0><<<16 * gy1, 512, 0, stream>>>(fs_c, W8, lb, pr_c, bufA8, gy1, 192, 0,
                                                nullptr, nullptr, nullptr);
    k_gemmF<1, 0><<<16 * gy2, 512, 0, stream>>>(bufA8, W8 + wlz, lb + 8192, pr_c, bufB8,
                                                gy2, 192 + 64, 64, nullptr, nullptr, nullptr);
    k_gemmF<1, 1><<<16 * gy2, 512, 0, stream>>>(bufB8, W8 + 2 * wlz, lb + 16384, pr_c, bufA8,
                                                gy2, 192 + 128, 128, WfcT8, WfaT8, out_c);
  }
}

// Round 15
// 690.057 us; speedup vs baseline: 1.2520x; 1.1576x over previous
//
#include <hip/hip_runtime.h>
#include <hip/hip_bf16.h>

typedef float f32x4 __attribute__((ext_vector_type(4)));
typedef float f32x2 __attribute__((ext_vector_type(2)));
typedef int   i32x4 __attribute__((ext_vector_type(4)));
typedef int   i32x8 __attribute__((ext_vector_type(8)));

#define LOG_SQRT_2PI 0.91893853320467274f

static constexpr int BSZ  = 16384;
static constexpr int OBSN = 376;
static constexpr int HD   = 512;
static constexpr int NACT = 17;

__device__ __forceinline__ unsigned char f2fp8(float v) {
  return (unsigned char)(__builtin_amdgcn_cvt_pk_fp8_f32(v, v, 0, false) & 0xFF);
}

__device__ __forceinline__ void gl16(const unsigned char* g, unsigned char* l) {
  __builtin_amdgcn_global_load_lds((const __attribute__((address_space(1))) void*)g,
                                   (__attribute__((address_space(3))) void*)l, 16, 0, 0);
}

// XCD-aware tile remap. Requires grid % 8 == 0.
__device__ __forceinline__ void xcd_map(int id, int gx, int gy, int& bx, int& by, int& bz) {
  int p = id & 7, l = id >> 3;
  bx = l % gx;
  int g = (l / gx) * 8 + p;
  by = g % gy;
  bz = g / gy;
}

// ---------------- prep kernels ----------------

// x [B,376] f32 -> [B,512] fp8 (zero pad)
__global__ void k_cvt_pad8(const float* __restrict__ src, unsigned char* __restrict__ dst) {
  long i = (long)blockIdx.x * 256 + threadIdx.x;
  if (i >= (long)BSZ * HD) return;
  long r = i >> 9;
  int  c = (int)(i & 511);
  dst[i] = f2fp8(c < OBSN ? src[r * OBSN + c] : 0.f);
}

// dst[n][k] = fp8(scale * src[k][n]); zero for k >= K. batched via blockIdx.z.
__global__ void k_packT8(const float* __restrict__ src, unsigned char* __restrict__ dst,
                         int K, int N, int Kpad, long sstride, long dstride, float scale) {
  __shared__ float t[32][33];
  src += (long)blockIdx.z * sstride;
  dst += (long)blockIdx.z * dstride;
  int k0 = blockIdx.y * 32, n0 = blockIdx.x * 32;
#pragma unroll
  for (int ii = 0; ii < 4; ++ii) {
    int i = ii * 8 + threadIdx.y;
    int k = k0 + i, n = n0 + threadIdx.x;
    t[i][threadIdx.x] = (k < K && n < N) ? src[(long)k * N + n] : 0.f;
  }
  __syncthreads();
#pragma unroll
  for (int ii = 0; ii < 4; ++ii) {
    int i = ii * 8 + threadIdx.y;
    int n = n0 + i, k = k0 + threadIdx.x;
    if (n < N && k < Kpad) dst[(long)n * Kpad + k] = f2fp8(scale * t[threadIdx.x][i]);
  }
}

// base-net weights -> FRAGMENT-PACKED fp8 x16, via LDS transpose (coalesced reads,
// contiguous 32 B fragment writes). Bit-exact verified.
__global__ void k_packwF(const float* __restrict__ aW, const float* __restrict__ cW,
                         unsigned char* __restrict__ dst) {
  __shared__ unsigned char sT[128 * 144];
  const int tid = threadIdx.x;            // 256
  const int z = blockIdx.z;               // 0..47
  const int t = blockIdx.y;               // 0..3
  const int ng = blockIdx.x;              // 0..3
  const int layer = z >> 4, zz = z & 15, net = zz >> 3, m = zz & 7;
  const float* src = (net ? aW : cW) + (long)(layer * 8 + m) * 262144;
#pragma unroll
  for (int i = 0; i < 64; ++i) {
    int lin = i * 256 + tid;
    int kl = lin >> 7, nl = lin & 127;
    float v = src[(long)(t * 128 + kl) * 512 + ng * 128 + nl];
    sT[nl * 144 + kl] = f2fp8(16.f * v);
  }
  __syncthreads();
#pragma unroll
  for (int f = 0; f < 2; ++f) {
    int fid = f * 256 + tid;
    int lane = fid & 63, nb_l = fid >> 6;
    int n_l = nb_l * 16 + (lane & 15);
    int klo = ((lane >> 4) & 3) * 32;
    uint4 lo = *(const uint4*)&sT[n_l * 144 + klo];
    uint4 hi = *(const uint4*)&sT[n_l * 144 + klo + 16];
    int nb = ng * 8 + nb_l;
    unsigned char* d = dst + ((((long)z * 4 + t) * 32 + nb) * 64 + lane) * 32;
    *(uint4*)d = lo;
    *(uint4*)(d + 16) = hi;
  }
}

// merged small packs: lb (merged biases), head weights (permuted-k), routing bias
__global__ void k_packmisc(const float* __restrict__ a_b, const float* __restrict__ c_b,
                           const float* __restrict__ aWf, const float* __restrict__ cWf,
                           const float* __restrict__ a_rb, const float* __restrict__ c_rb,
                           float* __restrict__ lb, unsigned char* __restrict__ dsta,
                           unsigned char* __restrict__ dstc, float* __restrict__ rb) {
  int i = blockIdx.x * 256 + threadIdx.x;
  if (i < 24576) {
    int layer = i >> 13, zz = (i >> 9) & 15, n = i & 511;
    int net = zz >> 3, m = zz & 7;
    lb[i] = (net ? a_b : c_b)[(layer * 8 + m) * 512 + n];
  } else if (i < 24576 + 131072) {
    int j = i - 24576;
    int n = j >> 12, kn = j & 4095;
    int hb = kn >> 9, rem = kn & 511, m = rem >> 6, u = kn & 63;
    int ko = m * 512 + hb * 64 + u;
    dsta[j] = (n < NACT) ? f2fp8(64.f * aWf[(long)ko * NACT + n]) : (unsigned char)0;
    dstc[j] = (n < 1)    ? f2fp8(64.f * cWf[ko])                  : (unsigned char)0;
  } else if (i < 24576 + 131072 + 384) {
    int j = i - 24576 - 131072;
    rb[j] = (j < 192) ? a_rb[j] : c_rb[j - 192];
  }
}

// out init: bias sums for actor/critic heads + logstd constants (cols 17/18).
__global__ void k_initout2(const float* __restrict__ a_bf, const float* __restrict__ c_bf,
                           const float* __restrict__ ls, float* __restrict__ out) {
  long i = (long)blockIdx.x * 256 + threadIdx.x;   // BSZ*20
  if (i >= (long)BSZ * 20) return;
  int o = (int)(i % 20);
  float v = 0.f;
  if (o < NACT) {
    for (int m = 0; m < 8; ++m) v += a_bf[m * NACT + o];
  } else if (o == 19) {
    for (int m = 0; m < 8; ++m) v += c_bf[m];
  } else if (o == 17) {
    for (int a = 0; a < NACT; ++a) v += -ls[a] - LOG_SQRT_2PI;
  } else {
    for (int a = 0; a < NACT; ++a) v += 0.5f + LOG_SQRT_2PI + ls[a];
  }
  out[i] = v;
}

// ---------------- unified MX fp8 GEMM (LDS path): encoder / routing ----------------
// OP: 1 = tanh -> fp8 (encoder-1); 5 = tanh->fp8 AND fp8(relu(tanh*temb)) (encoder-2)
//     4 = softmax over col-octets -> f32 (routing)
template <int OP>
__global__ __launch_bounds__(256, 4)
void k_gemm8(const unsigned char* __restrict__ A, const unsigned char* __restrict__ Bt,
             void* __restrict__ Cv, const float* __restrict__ bias,
             int N, int K, int lda, int ldc, int gx, int gy,
             const int* __restrict__ tidx, const float* __restrict__ temb,
             unsigned char* __restrict__ out2) {
  __shared__ alignas(16) unsigned char sA[128 * 128];
  __shared__ alignas(16) unsigned char sB[128 * 128];
  int bx, by, z;
  xcd_map(blockIdx.x, gx, gy, bx, by, z);
  const int tid  = threadIdx.x;
  const int wave = tid >> 6, lane = tid & 63;
  const int wr = (wave >> 1) * 64, wc = (wave & 1) * 64;
  const int row0 = by * 128, col0 = bx * 128;
  const int lcol = lane & 15, quad = lane >> 4;
  const int sw7 = lcol & 7;
  const int c0 = ((2 * quad)     ^ sw7) * 16;
  const int c1 = ((2 * quad + 1) ^ sw7) * 16;
  const int raA0 = (wr + lcol) * 128 + c0, raA1 = (wr + lcol) * 128 + c1;
  const int rbB0 = (wc + lcol) * 128 + c0, rbB1 = (wc + lcol) * 128 + c1;
  int aOff[4], bOff[4];
#pragma unroll
  for (int i = 0; i < 4; ++i) {
    int u = i * 256 + tid;
    int r = u >> 3, gc = (u & 7) ^ (r & 7);
    aOff[i] = (row0 + r) * lda + gc * 16;
    bOff[i] = (col0 + r) * K + gc * 16;
  }

  f32x4 acc[4][4] = {};

  for (int kt = 0; kt < K; kt += 128) {
#pragma unroll
    for (int i = 0; i < 4; ++i) gl16(A + aOff[i] + kt, &sA[i * 4096 + tid * 16]);
#pragma unroll
    for (int i = 0; i < 4; ++i) gl16(Bt + bOff[i] + kt, &sB[i * 4096 + tid * 16]);
    __syncthreads();
    i32x8 bv[4];
#pragma unroll
    for (int ni = 0; ni < 4; ++ni) {
      i32x4 blo = *(const i32x4*)&sB[rbB0 + ni * 2048];
      i32x4 bhi = *(const i32x4*)&sB[rbB1 + ni * 2048];
      bv[ni] = (i32x8){blo[0], blo[1], blo[2], blo[3], bhi[0], bhi[1], bhi[2], bhi[3]};
    }
#pragma unroll
    for (int mi = 0; mi < 4; ++mi) {
      i32x4 alo = *(const i32x4*)&sA[raA0 + mi * 2048];
      i32x4 ahi = *(const i32x4*)&sA[raA1 + mi * 2048];
      i32x8 af = (i32x8){alo[0], alo[1], alo[2], alo[3], ahi[0], ahi[1], ahi[2], ahi[3]};
#pragma unroll
      for (int ni = 0; ni < 4; ++ni)
        acc[mi][ni] = __builtin_amdgcn_mfma_scale_f32_16x16x128_f8f6f4(
            bv[ni], af, acc[mi][ni], 0, 0, 0, 0x7F, 0, 0x7F);
    }
    __syncthreads();
  }

#pragma unroll
  for (int ni = 0; ni < 4; ++ni) {
    int colb = col0 + wc + ni * 16 + quad * 4;
    if (colb >= N) continue;
    float4 bw = *(const float4*)&bias[colb];
#pragma unroll
    for (int mi = 0; mi < 4; ++mi) {
      int rowg = row0 + wr + mi * 16 + lcol;
      float v0 = acc[mi][ni][0] * 0.0625f + bw.x;
      float v1 = acc[mi][ni][1] * 0.0625f + bw.y;
      float v2 = acc[mi][ni][2] * 0.0625f + bw.z;
      float v3 = acc[mi][ni][3] * 0.0625f + bw.w;
      long idx = (long)rowg * ldc + colb;
      if (OP == 1) {
        float t0 = tanhf(v0), t1 = tanhf(v1), t2 = tanhf(v2), t3 = tanhf(v3);
        unsigned d = __builtin_amdgcn_cvt_pk_fp8_f32(t0, t1, 0, false);
        d = __builtin_amdgcn_cvt_pk_fp8_f32(t2, t3, d, true);
        *(unsigned*)&((unsigned char*)Cv)[idx] = d;
      } else if (OP == 5) {
        float t0 = tanhf(v0), t1 = tanhf(v1), t2 = tanhf(v2), t3 = tanhf(v3);
        unsigned d = __builtin_amdgcn_cvt_pk_fp8_f32(t0, t1, 0, false);
        d = __builtin_amdgcn_cvt_pk_fp8_f32(t2, t3, d, true);
        *(unsigned*)&((unsigned char*)Cv)[idx] = d;
        int tk = tidx[rowg];
        float4 te = *(const float4*)&temb[(long)tk * HD + colb];
        unsigned e = __builtin_amdgcn_cvt_pk_fp8_f32(fmaxf(t0 * te.x, 0.f), fmaxf(t1 * te.y, 0.f), 0, false);
        e = __builtin_amdgcn_cvt_pk_fp8_f32(fmaxf(t2 * te.z, 0.f), fmaxf(t3 * te.w, 0.f), e, true);
        *(unsigned*)&out2[idx] = e;
      } else if (OP == 4) {
        float mx = fmaxf(fmaxf(v0, v1), fmaxf(v2, v3));
        mx = fmaxf(mx, __shfl_xor(mx, 16));
        float e0 = __expf(v0 - mx), e1 = __expf(v1 - mx), e2 = __expf(v2 - mx), e3 = __expf(v3 - mx);
        float s = e0 + e1 + e2 + e3;
        s += __shfl_xor(s, 16);
        float inv = 1.f / s;
        *(float4*)&((float*)Cv)[idx] = make_float4(e0 * inv, e1 * inv, e2 * inv, e3 * inv);
      }
    }
  }
}

// ---------------- FUSED base-net layer: GEMM (8 modules) + routed combine (+head) ----
// R12 structure (8 KB/wave single staging) with COUNTED vmcnt: gl16 issue (pinned
// first) -> bv weight loads -> vmcnt(8) certifies only the staging (8 oldest), bv
// latency hides under the af ds_reads. setprio around MFMAs, pk-fma combine.
template <int AMODE, int HEAD>
__global__ __launch_bounds__(512, 4)
void k_gemmF(const unsigned char* __restrict__ A, const unsigned char* __restrict__ Wp,
             const float* __restrict__ lb, const float* __restrict__ probs,
             unsigned char* __restrict__ g, int gy, int poffC, int poffA,
             const unsigned char* __restrict__ Wfc, const unsigned char* __restrict__ Wfa,
             float* __restrict__ outp) {
  __shared__ alignas(16) unsigned char sL[AMODE ? 65536 : 32768];
  int hb, slab, net;
  xcd_map(blockIdx.x, 8, gy, hb, slab, net);
  const int tid = threadIdx.x;
  const int w = tid >> 6, lane = tid & 63;
  const int lcol = lane & 15, quad = lane >> 4;
  const int ln3 = lane >> 3, sl = lane & 7;
  const int row0 = slab * 64;
  const int h0 = hb * 64;
  const int sw7 = lcol & 7;
  const int c0 = ((2 * quad)     ^ sw7) * 16;
  const int c1 = ((2 * quad + 1) ^ sw7) * 16;
  const int ch = sl ^ ln3;
  const unsigned char* wbase =
      Wp + (((long)(net * 8 + w) * 4 * 32 + hb * 4) * 64 + lane) * 32;

  f32x4 acc[4][4] = {};

  if (AMODE == 0) {
#pragma unroll
    for (int i = 0; i < 4; ++i) {
      int vb = w * 4 + i;
      int rr = (vb & 7) * 8 + ln3;
      gl16(A + (row0 + rr) * 512 + (vb >> 3) * 128 + ch * 16, &sL[(vb * 64 + lane) * 16]);
    }
    __syncthreads();
#pragma unroll
    for (int t = 0; t < 4; ++t) {
      i32x8 bv[4];
#pragma unroll
      for (int ni = 0; ni < 4; ++ni) {
        i32x4 lo = *(const i32x4*)(wbase + t * 65536 + ni * 2048);
        i32x4 hi = *(const i32x4*)(wbase + t * 65536 + ni * 2048 + 16);
        bv[ni] = (i32x8){lo[0], lo[1], lo[2], lo[3], hi[0], hi[1], hi[2], hi[3]};
      }
      __builtin_amdgcn_s_setprio(1);
#pragma unroll
      for (int mi = 0; mi < 4; ++mi) {
        int ra = t * 8192 + (mi * 16 + lcol) * 128;
        i32x4 lo = *(const i32x4*)&sL[ra + c0];
        i32x4 hi = *(const i32x4*)&sL[ra + c1];
        i32x8 af = (i32x8){lo[0], lo[1], lo[2], lo[3], hi[0], hi[1], hi[2], hi[3]};
#pragma unroll
        for (int ni = 0; ni < 4; ++ni)
          acc[mi][ni] = __builtin_amdgcn_mfma_scale_f32_16x16x128_f8f6f4(
              bv[ni], af, acc[mi][ni], 0, 0, 0, 0x7F, 0, 0x7F);
      }
      __builtin_amdgcn_s_setprio(0);
    }
  } else {
    // wave-private staging: 8 KB region per wave, counted vmcnt(8) per K-tile.
    const unsigned char* abase = A + (long)(row0 + ln3) * 8192 + net * 4096 +
                                 w * 64 + ((ch >> 2) + (ch & 3) * 0) * 0 +   // (no-op, keep shape)
                                 w * 0 + ch * 16;
    // NOTE: layout identical to R12: row-major g, module slice at net*4096 + w*512.
    abase = A + (long)(row0 + ln3) * 8192 + net * 4096 + w * 512 + ch * 16;
    unsigned char* dbase = &sL[w * 8192 + lane * 16];
#pragma unroll 1
    for (int t = 0; t < 4; ++t) {
#pragma unroll
      for (int i = 0; i < 8; ++i)
        gl16(abase + i * 8 * 8192 + t * 128, dbase + i * 1024);
      __builtin_amdgcn_sched_barrier(0);           // pin: staging ops are the 8 oldest
      i32x8 bv[4];
#pragma unroll
      for (int ni = 0; ni < 4; ++ni) {
        i32x4 lo = *(const i32x4*)(wbase + t * 65536 + ni * 2048);
        i32x4 hi = *(const i32x4*)(wbase + t * 65536 + ni * 2048 + 16);
        bv[ni] = (i32x8){lo[0], lo[1], lo[2], lo[3], hi[0], hi[1], hi[2], hi[3]};
      }
      asm volatile("s_waitcnt vmcnt(8)" ::: "memory");   // staging landed; bv still in flight
      __builtin_amdgcn_sched_barrier(0);
      __builtin_amdgcn_s_setprio(1);
#pragma unroll
      for (int mi = 0; mi < 4; ++mi) {
        int ra = w * 8192 + (mi * 16 + lcol) * 128;
        i32x4 lo = *(const i32x4*)&sL[ra + c0];
        i32x4 hi = *(const i32x4*)&sL[ra + c1];
        i32x8 af = (i32x8){lo[0], lo[1], lo[2], lo[3], hi[0], hi[1], hi[2], hi[3]};
#pragma unroll
        for (int ni = 0; ni < 4; ++ni)
          acc[mi][ni] = __builtin_amdgcn_mfma_scale_f32_16x16x128_f8f6f4(
              bv[ni], af, acc[mi][ni], 0, 0, 0, 0x7F, 0, 0x7F);
      }
      __builtin_amdgcn_s_setprio(0);
    }
  }

  __syncthreads();   // staging dead; reuse sL[0,32K) as sO (and sG for HEAD)

  // ---- epilogue A: relu -> fp8 -> sO[j=w][64 r][16 dwords], dword-slot XOR (r&14) ----
#pragma unroll
  for (int ni = 0; ni < 4; ++ni) {
    int col = ni * 16 + quad * 4;
    float4 bw = *(const float4*)&lb[(net * 8 + w) * 512 + h0 + col];
    int sd = ni * 4 + quad;
#pragma unroll
    for (int mi = 0; mi < 4; ++mi) {
      int row = mi * 16 + lcol;
      float v0 = fmaxf(acc[mi][ni][0] * 0.0625f + bw.x, 0.f);
      float v1 = fmaxf(acc[mi][ni][1] * 0.0625f + bw.y, 0.f);
      float v2 = fmaxf(acc[mi][ni][2] * 0.0625f + bw.z, 0.f);
      float v3 = fmaxf(acc[mi][ni][3] * 0.0625f + bw.w, 0.f);
      unsigned d = __builtin_amdgcn_cvt_pk_fp8_f32(v0, v1, 0, false);
      d = __builtin_amdgcn_cvt_pk_fp8_f32(v2, v3, d, true);
      *(unsigned*)&sL[w * 4096 + row * 64 + ((sd ^ (row & 14)) << 2)] = d;
    }
  }
  __syncthreads();

  // ---- epilogue B: routed combine from LDS (packed f32x2 FMA); wave w = module i ----
  const int poff = net ? poffA : poffC;
#pragma unroll
  for (int k = 0; k < 8; ++k) {
    const int r = k * 8 + ln3;
    const float* pr = &probs[(long)(row0 + r) * 384 + poff + w * 8];
    float4 pA = *(const float4*)pr;
    float4 pB = *(const float4*)(pr + 4);
    float p8[8] = {pA.x, pA.y, pA.z, pA.w, pB.x, pB.y, pB.z, pB.w};
    f32x2 ga2[4] = {};
#pragma unroll
    for (int j = 0; j < 8; ++j) {
      uint2 o2 = *(const uint2*)&sL[j * 4096 + r * 64 + (((sl * 2) ^ (r & 14)) << 2)];
      f32x2 pw2 = {p8[j], p8[j]};
      ga2[0] += pw2 * __builtin_amdgcn_cvt_pk_f32_fp8(o2.x, false);
      ga2[1] += pw2 * __builtin_amdgcn_cvt_pk_f32_fp8(o2.x, true);
      ga2[2] += pw2 * __builtin_amdgcn_cvt_pk_f32_fp8(o2.y, false);
      ga2[3] += pw2 * __builtin_amdgcn_cvt_pk_f32_fp8(o2.y, true);
    }
    unsigned lo = __builtin_amdgcn_cvt_pk_fp8_f32(ga2[0][0], ga2[0][1], 0, false);
    lo = __builtin_amdgcn_cvt_pk_fp8_f32(ga2[1][0], ga2[1][1], lo, true);
    unsigned hi = __builtin_amdgcn_cvt_pk_fp8_f32(ga2[2][0], ga2[2][1], 0, false);
    hi = __builtin_amdgcn_cvt_pk_fp8_f32(ga2[3][0], ga2[3][1], hi, true);
    if (HEAD) {
      *(uint2*)&sL[32768 + w * 4096 + r * 64 + (((sl * 2) ^ (r & 14)) << 2)] =
          make_uint2(lo, hi);
    } else {
      *(uint2*)&g[(long)(row0 + r) * 8192 + net * 4096 + w * 512 + h0 + sl * 8] =
          make_uint2(lo, hi);
    }
  }

  if (HEAD) {
    __syncthreads();
    const unsigned char* Wf = net ? Wfa : Wfc;
    const int ooff = net ? 0 : 19;
    const int mi = w & 3, kh = w >> 2;
    const int hrow = mi * 16 + lcol;
    f32x4 hacc[2] = {};
#pragma unroll
    for (int ks = 0; ks < 8; ++ks) {
      int j = kh * 4 + (ks >> 1);
      int u = (ks & 1) * 32 + quad * 8;
      int sd = u >> 2;
      long af = *(const long*)&sL[32768 + j * 4096 + hrow * 64 + ((sd ^ (hrow & 14)) << 2)];
      int kglob = hb * 512 + kh * 256 + ks * 32 + quad * 8;
      long bv0 = *(const long*)&Wf[(long)lcol * 4096 + kglob];
      hacc[0] = __builtin_amdgcn_mfma_f32_16x16x32_fp8_fp8(af, bv0, hacc[0], 0, 0, 0);
      if (net) {
        long bv1 = *(const long*)&Wf[(long)(16 + lcol) * 4096 + kglob];
        hacc[1] = __builtin_amdgcn_mfma_f32_16x16x32_fp8_fp8(af, bv1, hacc[1], 0, 0, 0);
      }
    }
    const int NOUTn = net ? NACT : 1;
#pragma unroll
    for (int ni = 0; ni < 2; ++ni) {
      if (ni == 1 && !net) break;
      int col = ni * 16 + lcol;
      if (col >= NOUTn) continue;
#pragma unroll
      for (int rr = 0; rr < 4; ++rr) {
        int row = row0 + mi * 16 + quad * 4 + rr;
        atomicAdd(&outp[(long)row * 20 + ooff + col], hacc[ni][rr] * 0.015625f);
      }
    }
  }
}

// ---------------- host ----------------

extern "C" void kernel_launch(void* const* d_in, const int* in_sizes, int n_in,
                              void* d_out, int out_size, void* d_ws, size_t ws_size,
                              hipStream_t stream) {
  const float* x        = (const float*)d_in[0];
  const int*   task_idx = (const int*)d_in[1];
  const float* enc_W1   = (const float*)d_in[2];
  const float* enc_b1   = (const float*)d_in[3];
  const float* enc_W2   = (const float*)d_in[4];
  const float* enc_b2   = (const float*)d_in[5];
  const float* task_emb = (const float*)d_in[6];
  const float* a_rW     = (const float*)d_in[7];
  const float* a_rb     = (const float*)d_in[8];
  const float* c_rW     = (const float*)d_in[9];
  const float* c_rb     = (const float*)d_in[10];
  const float* a_W      = (const float*)d_in[11];
  const float* a_b      = (const float*)d_in[12];
  const float* a_Wf     = (const float*)d_in[13];
  const float* a_bf     = (const float*)d_in[14];
  const float* c_W      = (const float*)d_in[15];
  const float* c_b      = (const float*)d_in[16];
  const float* c_Wf     = (const float*)d_in[17];
  const float* c_bf     = (const float*)d_in[18];
  const float* logstd   = (const float*)d_in[19];
  float* out = (float*)d_out;

  char* ws = (char*)d_ws;
  size_t off = 0;
  auto carve = [&](size_t bytes) {
    char* p = ws + off;
    off += (bytes + 255) & ~(size_t)255;
    return p;
  };
  // ---- fixed region ----
  unsigned char* W8 = (unsigned char*)carve((size_t)48 * 262144);   // frag-packed base weights
  unsigned char* W1T8 = (unsigned char*)carve((size_t)512 * 512);   // enc W1^T fp8 x16, K-pad 512
  unsigned char* W2T8 = (unsigned char*)carve((size_t)512 * 512);   // enc W2^T fp8 x16
  unsigned char* rWT8 = (unsigned char*)carve((size_t)384 * 512);   // routing W^T fp8 x16
  float* rball = (float*)carve(384 * 4);
  float* lb    = (float*)carve(3 * 16 * 512 * 4);                   // merged biases
  unsigned char* WfaT8 = (unsigned char*)carve((size_t)32 * 4096);  // head weights, perm-k
  unsigned char* WfcT8 = (unsigned char*)carve((size_t)32 * 4096);
  unsigned char* fs8 = (unsigned char*)carve((size_t)BSZ * HD);
  float* lgt   = (float*)carve((size_t)BSZ * 384 * 4);

  // ---- fp8 ping-pong region ([Bc, 8192] each) ----
  size_t remain = (ws_size > off) ? (ws_size - off) : 0;
  int Bc = 2048;
  for (int cand = BSZ; cand > 2048; cand >>= 1)
    if ((size_t)2 * cand * 8192 <= remain) { Bc = cand; break; }
  size_t half = (size_t)Bc * 8192;
  unsigned char* bufA8 = (unsigned char*)carve(half);
  unsigned char* bufB8 = (unsigned char*)carve(half);
  unsigned char* x8   = bufA8;   // [B,512] fp8, dead after enc1
  unsigned char* h18  = bufB8;   // [B,512] fp8, dead after enc2
  unsigned char* rel8 = bufA8;   // [B,512] fp8, dead after routing

  dim3 tb(32, 8);

  // ---- prep ----
  k_cvt_pad8<<<(int)(((long)BSZ * HD + 255) / 256), 256, 0, stream>>>(x, x8);
  k_packT8<<<dim3(16, 16, 1), tb, 0, stream>>>(enc_W1, W1T8, OBSN, 512, 512, 0, 0, 16.f);
  k_packT8<<<dim3(16, 16, 1), tb, 0, stream>>>(enc_W2, W2T8, 512, 512, 512, 0, 0, 16.f);
  k_packT8<<<dim3(2, 16, 3),  tb, 0, stream>>>(a_rW, rWT8,             512, 64, 512, 512 * 64, 64 * 512, 16.f);
  k_packT8<<<dim3(2, 16, 3),  tb, 0, stream>>>(c_rW, rWT8 + 192 * 512, 512, 64, 512, 512 * 64, 64 * 512, 16.f);
  k_packwF<<<dim3(4, 4, 48), 256, 0, stream>>>(a_W, c_W, W8);
  k_packmisc<<<610, 256, 0, stream>>>(a_b, c_b, a_Wf, c_Wf, a_rb, c_rb,
                                      lb, WfaT8, WfcT8, rball);
  k_initout2<<<(int)(((long)BSZ * 20 + 255) / 256), 256, 0, stream>>>(a_bf, c_bf, logstd, out);

  const int GY = BSZ / 128;
  // ---- encoder + routing (proven 3-dispatch chain) ----
  k_gemm8<1><<<4 * GY, 256, 0, stream>>>(x8, W1T8, h18, enc_b1, 512, 512, 512, 512,
                                         4, GY, nullptr, nullptr, nullptr);
  k_gemm8<5><<<4 * GY, 256, 0, stream>>>(h18, W2T8, fs8, enc_b2, 512, 512, 512, 512,
                                         4, GY, task_idx, task_emb, rel8);
  k_gemm8<4><<<3 * GY, 256, 0, stream>>>(rel8, rWT8, lgt, rball, 384, 512, 512, 384,
                                         3, GY, nullptr, nullptr, nullptr);

  // ---- base nets: fused GEMM+combine, layer 3 fuses heads ----
  const size_t wlz = (size_t)16 * 262144;
  for (int c0 = 0; c0 < BSZ; c0 += Bc) {
    const unsigned char* fs_c = fs8 + (long)c0 * 512;
    const float* pr_c  = lgt + (long)c0 * 384;
    float*       out_c = out + (long)c0 * 20;
    const int gyF = Bc / 64;

    k_gemmF<0, 0><<<16 * gyF, 512, 0, stream>>>(fs_c, W8, lb, pr_c, bufA8, gyF, 192, 0,
                                                nullptr, nullptr, nullptr);
    k_gemmF<1, 0><<<16 * gyF, 512, 0, stream>>>(bufA8, W8 + wlz, lb + 8192, pr_c, bufB8,
                                                gyF, 192 + 64, 64, nullptr, nullptr, nullptr);
    k_gemmF<1, 1><<<16 * gyF, 512, 0, stream>>>(bufB8, W8 + 2 * wlz, lb + 16384, pr_c, bufA8,
                                                gyF, 192 + 128, 128, WfcT8, WfaT8, out_c);
  }
}